// Round 1
// baseline (343.501 us; speedup 1.0000x reference)
//
#include <hip/hip_runtime.h>

// Problem constants (shapes fixed by the reference)
constexpr int D    = 128;   // node embedding dim
constexpr int K2   = 256;   // 2*D, layer-1 K
constexpr int H    = 256;   // hidden
constexpr int CLS  = 32;    // classes
constexpr int MT   = 64;    // edges per tile
constexpr int LSTR = 264;   // LDS row stride in ushort (256 + 8 pad -> 2-way banks, free)

typedef __attribute__((ext_vector_type(8))) __bf16 bf16x8;
typedef __attribute__((ext_vector_type(8))) unsigned short ushort8;
typedef __attribute__((ext_vector_type(4))) float f32x4;

static __device__ __forceinline__ unsigned short f2b(float f) {
  unsigned int u = __float_as_uint(f);
  u += 0x7FFFu + ((u >> 16) & 1u);   // RNE
  return (unsigned short)(u >> 16);
}

// ---------------- prep: weights fp32 -> bf16 in ws, + int64/int32 index sniff ----
__global__ void prep_weights(const float* __restrict__ W1, const float* __restrict__ W2,
                             const void* __restrict__ eidx,
                             unsigned short* __restrict__ W1b, unsigned short* __restrict__ W2b,
                             int* __restrict__ flag64) {
  int i = blockIdx.x * 256 + threadIdx.x;
  if (i < H * K2)  W1b[i] = f2b(W1[i]);
  if (i < CLS * H) W2b[i] = f2b(W2[i]);
  if (blockIdx.x == 0 && threadIdx.x == 0) {
    // node ids < 100000 < 2^31: if data is int64 little-endian, every odd u32 is 0.
    const unsigned int* p = (const unsigned int*)eidx;
    int is64 = 1;
    for (int j = 0; j < 64; ++j) if (p[2 * j + 1] != 0u) { is64 = 0; break; }
    *flag64 = is64;
  }
}

// ---------------- main fused kernel ------------------------------------------
// Per block: 4 waves, 64 edges. Wave w owns hidden rows [64w,64w+64).
// Layer 1 computed transposed: D1[n][m] = sum_k W1[n][k] * X[m][k]
//   A-frag = W1 rows (held in 128 VGPRs across the grid-stride loop)
//   B-frag = X from LDS (row-major [edge][k], k-contiguous per lane)
// Layer 2: D2[c][m] = sum_n W2[c][n] * Y[m][n], Y in LDS (overwrites X buffer).
__global__ __launch_bounds__(256, 2)
void edge_mlp(const float* __restrict__ emb, const void* __restrict__ eidx,
              const unsigned short* __restrict__ W1b, const unsigned short* __restrict__ W2b,
              const float* __restrict__ b1, const float* __restrict__ b2,
              const int* __restrict__ flag64,
              float* __restrict__ out, int E, int ntiles) {
  __shared__ unsigned short Xs[MT * LSTR];   // 33792 B, shared between X and Y phases

  const int tid  = threadIdx.x;
  const int lane = tid & 63;
  const int w    = tid >> 6;     // wave 0..3
  const int l16  = lane & 15;
  const int q    = lane >> 4;    // quad 0..3
  const int is64 = *flag64;

  // Persistent W1 A-fragments: afr[a][kk] covers hidden row 64w+16a+l16, k = 32kk+8q..+8
  bf16x8 afr[4][8];
  #pragma unroll
  for (int a = 0; a < 4; ++a) {
    const unsigned short* rp = W1b + (64 * w + 16 * a + l16) * K2 + q * 8;
    #pragma unroll
    for (int kk = 0; kk < 8; ++kk)
      afr[a][kk] = *(const bf16x8*)(rp + kk * 32);
  }
  // Bias init fragments (C-layout row = quad*4 + reg)
  f32x4 binit[4];
  #pragma unroll
  for (int a = 0; a < 4; ++a) binit[a] = *(const f32x4*)(b1 + 64 * w + 16 * a + 4 * q);
  f32x4 b2init[2];
  #pragma unroll
  for (int ct = 0; ct < 2; ++ct) b2init[ct] = *(const f32x4*)(b2 + 16 * ct + 4 * q);

  for (int t = blockIdx.x; t < ntiles; t += gridDim.x) {
    const int e0 = t * MT;

    // ---- stage X: gather fp32 node rows, convert to bf16, into LDS ----
    // 2048 chunks of 8 elements; 16 consecutive threads read one contiguous 512B node row.
    #pragma unroll
    for (int c = 0; c < 8; ++c) {
      int chunk = tid + c * 256;
      int m     = chunk >> 5;         // edge row 0..63
      int col8  = chunk & 31;         // 8-elem column group; <16 = src half, >=16 = dst half
      int e     = e0 + m; if (e >= E) e = E - 1;
      int iofs  = (col8 < 16) ? e : (E + e);
      long long node;
      if (is64) node = ((const long long*)eidx)[iofs];
      else      node = (long long)(((const int*)eidx)[iofs]);
      const float* gp = emb + (int)node * D + (col8 & 15) * 8;
      f32x4 lo = *(const f32x4*)gp;
      f32x4 hi = *(const f32x4*)(gp + 4);
      ushort8 v;
      v[0] = f2b(lo[0]); v[1] = f2b(lo[1]); v[2] = f2b(lo[2]); v[3] = f2b(lo[3]);
      v[4] = f2b(hi[0]); v[5] = f2b(hi[1]); v[6] = f2b(hi[2]); v[7] = f2b(hi[3]);
      *(ushort8*)&Xs[m * LSTR + col8 * 8] = v;
    }
    __syncthreads();

    // ---- layer 1 MFMAs ----
    f32x4 acc[4][4];
    #pragma unroll
    for (int a = 0; a < 4; ++a)
      #pragma unroll
      for (int tt = 0; tt < 4; ++tt) acc[a][tt] = binit[a];

    #pragma unroll
    for (int tt = 0; tt < 4; ++tt) {
      #pragma unroll
      for (int kk = 0; kk < 8; ++kk) {
        bf16x8 bfrag = *(const bf16x8*)&Xs[(16 * tt + l16) * LSTR + kk * 32 + q * 8];
        #pragma unroll
        for (int a = 0; a < 4; ++a)
          acc[a][tt] = __builtin_amdgcn_mfma_f32_16x16x32_bf16(afr[a][kk], bfrag, acc[a][tt], 0, 0, 0);
      }
    }
    __syncthreads();   // all X reads complete before Y overwrites the buffer

    // ---- ReLU + bf16, write Y[m][n] (packed: 4 consecutive n per lane) ----
    #pragma unroll
    for (int a = 0; a < 4; ++a) {
      int n0 = 64 * w + 16 * a + 4 * q;
      #pragma unroll
      for (int tt = 0; tt < 4; ++tt) {
        f32x4 v = acc[a][tt];
        float x0 = fmaxf(v[0], 0.f), x1 = fmaxf(v[1], 0.f);
        float x2 = fmaxf(v[2], 0.f), x3 = fmaxf(v[3], 0.f);
        unsigned int p0 = (unsigned int)f2b(x0) | ((unsigned int)f2b(x1) << 16);
        unsigned int p1 = (unsigned int)f2b(x2) | ((unsigned int)f2b(x3) << 16);
        int m = 16 * tt + l16;
        uint2 pp; pp.x = p0; pp.y = p1;
        *(uint2*)&Xs[m * LSTR + n0] = pp;
      }
    }
    __syncthreads();

    // ---- layer 2: wave w handles edges [16w,16w+16), all 32 classes ----
    f32x4 acc2[2];
    acc2[0] = b2init[0]; acc2[1] = b2init[1];
    const int mrow = 16 * w + l16;
    #pragma unroll
    for (int kk = 0; kk < 8; ++kk) {
      bf16x8 yfrag = *(const bf16x8*)&Xs[mrow * LSTR + kk * 32 + q * 8];
      #pragma unroll
      for (int ct = 0; ct < 2; ++ct) {
        bf16x8 wf = *(const bf16x8*)(W2b + (16 * ct + l16) * H + kk * 32 + q * 8);
        acc2[ct] = __builtin_amdgcn_mfma_f32_16x16x32_bf16(wf, yfrag, acc2[ct], 0, 0, 0);
      }
    }
    int e = e0 + mrow;
    if (e < E) {
      #pragma unroll
      for (int ct = 0; ct < 2; ++ct)
        *(f32x4*)(out + e * CLS + 16 * ct + 4 * q) = acc2[ct];   // 4 consecutive classes
    }
    __syncthreads();   // Xs reused as X next iteration
  }
}

// ---------------- safety fallback (only if ws is too small): naive fp32 ------
__global__ void edge_mlp_naive(const float* __restrict__ emb, const void* __restrict__ eidx,
                               const float* __restrict__ W1, const float* __restrict__ b1,
                               const float* __restrict__ W2, const float* __restrict__ b2,
                               float* __restrict__ out, int E) {
  __shared__ float x[K2];
  __shared__ float y[H];
  __shared__ int flag;
  int e = blockIdx.x;
  if (threadIdx.x == 0) {
    const unsigned int* p = (const unsigned int*)eidx;
    int is64 = 1;
    for (int j = 0; j < 16; ++j) if (p[2 * j + 1] != 0u) { is64 = 0; break; }
    flag = is64;
  }
  __syncthreads();
  int tid = threadIdx.x;
  long long s, d;
  if (flag) { s = ((const long long*)eidx)[e]; d = ((const long long*)eidx)[E + e]; }
  else      { s = ((const int*)eidx)[e];       d = ((const int*)eidx)[E + e]; }
  if (tid < D) { x[tid] = emb[(int)s * D + tid]; x[D + tid] = emb[(int)d * D + tid]; }
  __syncthreads();
  // hidden
  {
    float acc = b1[tid];
    const float* wr = W1 + tid * K2;
    for (int k = 0; k < K2; ++k) acc += x[k] * wr[k];
    y[tid] = fmaxf(acc, 0.f);
  }
  __syncthreads();
  if (tid < CLS) {
    float acc = b2[tid];
    const float* wr = W2 + tid * H;
    for (int k = 0; k < H; ++k) acc += y[k] * wr[k];
    out[e * CLS + tid] = acc;
  }
}

extern "C" void kernel_launch(void* const* d_in, const int* in_sizes, int n_in,
                              void* d_out, int out_size, void* d_ws, size_t ws_size,
                              hipStream_t stream) {
  const float* emb  = (const float*)d_in[0];
  const void*  eidx = d_in[1];
  const float* W1   = (const float*)d_in[2];
  const float* b1   = (const float*)d_in[3];
  const float* W2   = (const float*)d_in[4];
  const float* b2   = (const float*)d_in[5];
  float* out = (float*)d_out;
  const int E = in_sizes[1] / 2;

  const size_t ws_need = (size_t)(H * K2 + CLS * H) * sizeof(unsigned short) + 64;
  if (ws_size < ws_need) {
    // insurance path: correct but slow
    edge_mlp_naive<<<E, H, 0, stream>>>(emb, eidx, W1, b1, W2, b2, out, E);
    return;
  }

  unsigned short* W1b = (unsigned short*)d_ws;
  unsigned short* W2b = W1b + H * K2;
  int* flag64 = (int*)(W2b + CLS * H);

  prep_weights<<<(H * K2 + 255) / 256, 256, 0, stream>>>(W1, W2, eidx, W1b, W2b, flag64);

  const int ntiles = (E + MT - 1) / MT;
  edge_mlp<<<1024, 256, 0, stream>>>(emb, eidx, W1b, W2b, b1, b2, flag64, out, E, ntiles);
}

// Round 2
// 320.573 us; speedup vs baseline: 1.0715x; 1.0715x over previous
//
#include <hip/hip_runtime.h>

constexpr int D    = 128;   // node embedding dim
constexpr int K2   = 256;   // 2*D, layer-1 K
constexpr int H    = 256;   // hidden
constexpr int CLS  = 32;    // classes
constexpr int MT   = 64;    // edges per tile
constexpr int LSTR = 264;   // (fallback kernel only) padded LDS stride in ushort

typedef __attribute__((ext_vector_type(8))) __bf16 bf16x8;
typedef __attribute__((ext_vector_type(8))) unsigned short ushort8;
typedef __attribute__((ext_vector_type(4))) float f32x4;

static __device__ __forceinline__ unsigned short f2b(float f) {
  unsigned int u = __float_as_uint(f);
  u += 0x7FFFu + ((u >> 16) & 1u);   // RNE
  return (unsigned short)(u >> 16);
}

static __device__ __forceinline__ void gld_lds16(const unsigned short* gp, unsigned short* lp) {
  __builtin_amdgcn_global_load_lds(
      (const __attribute__((address_space(1))) void*)gp,
      (__attribute__((address_space(3))) void*)lp, 16, 0, 0);
}

// ---------------- prep kernels ------------------------------------------------
__global__ void prep_weights(const float* __restrict__ W1, const float* __restrict__ W2,
                             const void* __restrict__ eidx,
                             unsigned short* __restrict__ W1b, unsigned short* __restrict__ W2b,
                             int* __restrict__ flag64) {
  int i = blockIdx.x * 256 + threadIdx.x;
  if (i < H * K2)  W1b[i] = f2b(W1[i]);
  if (i < CLS * H) W2b[i] = f2b(W2[i]);
  if (blockIdx.x == 0 && threadIdx.x == 0) {
    const unsigned int* p = (const unsigned int*)eidx;
    int is64 = 1;
    for (int j = 0; j < 64; ++j) if (p[2 * j + 1] != 0u) { is64 = 0; break; }
    *flag64 = is64;
  }
}

__global__ void prep_table(const float* __restrict__ emb, unsigned short* __restrict__ tab, int n8) {
  int i = blockIdx.x * 256 + threadIdx.x;
  if (i < n8) {
    const float* gp = emb + (size_t)i * 8;
    f32x4 lo = *(const f32x4*)gp, hi = *(const f32x4*)(gp + 4);
    ushort8 v;
    v[0] = f2b(lo[0]); v[1] = f2b(lo[1]); v[2] = f2b(lo[2]); v[3] = f2b(lo[3]);
    v[4] = f2b(hi[0]); v[5] = f2b(hi[1]); v[6] = f2b(hi[2]); v[7] = f2b(hi[3]);
    *(ushort8*)(tab + (size_t)i * 8) = v;
  }
}

__global__ void prep_idx(const void* __restrict__ eidx, int* __restrict__ idx32, int n) {
  __shared__ int sflag;
  if (threadIdx.x == 0) {
    const unsigned int* p = (const unsigned int*)eidx;
    int is64 = 1;
    for (int j = 0; j < 64; ++j) if (p[2 * j + 1] != 0u) { is64 = 0; break; }
    sflag = is64;
  }
  __syncthreads();
  int j = blockIdx.x * 256 + threadIdx.x;
  if (j < n) idx32[j] = sflag ? (int)((const long long*)eidx)[j] : ((const int*)eidx)[j];
}

// ---------------- main fused kernel (v2) --------------------------------------
// 4 waves, 64 edges/tile. X tiles double-buffered in LDS, staged via
// global_load_lds(16B) from a pre-converted bf16 node table. LDS rows are
// unpadded (512 B) with a 16B-granule XOR swizzle: data granule g of row m
// lives at slot (g&16)|((g^ (m&15))&15) -> all access patterns conflict-free.
// Layer 1 transposed: wave w holds W1 rows [64w,64w+64) in 128 VGPRs.
__global__ __launch_bounds__(256, 2)
void edge_mlp2(const unsigned short* __restrict__ tab, const int* __restrict__ idx32,
               const unsigned short* __restrict__ W1b, const unsigned short* __restrict__ W2b,
               const float* __restrict__ b1, const float* __restrict__ b2,
               float* __restrict__ out, int E, int ntiles) {
  __shared__ unsigned short Xs[2][MT * 256];   // 2 x 32 KB

  const int tid  = threadIdx.x;
  const int lane = tid & 63;
  const int w    = tid >> 6;
  const int l16  = lane & 15;
  const int q    = lane >> 4;

  // Persistent W1 A-fragments: hidden row 64w+16a+l16, k = 32kk+8q..+8
  bf16x8 afr[4][8];
  #pragma unroll
  for (int a = 0; a < 4; ++a) {
    const unsigned short* rp = W1b + (64 * w + 16 * a + l16) * K2 + q * 8;
    #pragma unroll
    for (int kk = 0; kk < 8; ++kk)
      afr[a][kk] = *(const bf16x8*)(rp + kk * 32);
  }
  f32x4 binit[4];
  #pragma unroll
  for (int a = 0; a < 4; ++a) binit[a] = *(const f32x4*)(b1 + 64 * w + 16 * a + 4 * q);
  f32x4 b2init[2];
  #pragma unroll
  for (int ct = 0; ct < 2; ++ct) b2init[ct] = *(const f32x4*)(b2 + 16 * ct + 4 * q);

  // staging geometry (per wave: its 16 edges, 8 instrs x 2 edges x 1KB LDS)
  const int G    = lane & 31;        // LDS slot granule within row
  const int half = G >> 4;           // 0 = head node, 1 = tail node
  const int sub  = lane >> 5;        // which of the 2 edges in this instr

  auto stage = [&](int t, unsigned short* Xb) {
    #pragma unroll
    for (int c = 0; c < 8; ++c) {
      int mrow = 16 * w + 2 * c + sub;
      int e = t * MT + mrow; if (e >= E) e = E - 1;
      int id = idx32[half ? (E + e) : e];
      // source granule = slot granule un-swizzled by row key (m&15)
      const unsigned short* gp = tab + (size_t)id * D + ((G ^ mrow) & 15) * 8;
      unsigned short* lp = &Xs[0][0] + (Xb - &Xs[0][0]) + (16 * w + 2 * c) * 256;
      gld_lds16(gp, lp);
    }
  };

  int buf = 0;
  int t0 = blockIdx.x;
  if (t0 < ntiles) stage(t0, &Xs[0][0]);

  for (int t = t0; t < ntiles; t += gridDim.x) {
    __syncthreads();   // staging(t) drained (vmcnt), prev tile's reads done
    unsigned short* Xb = &Xs[buf][0];
    int tn = t + gridDim.x;
    if (tn < ntiles) stage(tn, &Xs[buf ^ 1][0]);   // fire-and-forget into other buffer

    // ---- layer 1 ----
    f32x4 acc[4][4];
    #pragma unroll
    for (int a = 0; a < 4; ++a)
      #pragma unroll
      for (int tt = 0; tt < 4; ++tt) acc[a][tt] = binit[a];

    #pragma unroll
    for (int tt = 0; tt < 4; ++tt) {
      const unsigned short* rowp = Xb + (16 * tt + l16) * 256;
      #pragma unroll
      for (int kk = 0; kk < 8; ++kk) {
        int slot = (4 * kk + q) ^ l16;               // swizzled slot (bit4 preserved)
        bf16x8 bfrag = *(const bf16x8*)(rowp + slot * 8);
        #pragma unroll
        for (int a = 0; a < 4; ++a)
          acc[a][tt] = __builtin_amdgcn_mfma_f32_16x16x32_bf16(afr[a][kk], bfrag, acc[a][tt], 0, 0, 0);
      }
    }
    __syncthreads();   // layer-1 reads complete before Y overwrites Xb

    // ---- ReLU + bf16 -> Y[m][n] in Xb (swizzled) ----
    #pragma unroll
    for (int a = 0; a < 4; ++a) {
      int dg   = 8 * w + 2 * a + (q >> 1);           // data granule of this lane's 8B
      int qodd = (q & 1) * 4;                        // ushort offset within granule
      #pragma unroll
      for (int tt = 0; tt < 4; ++tt) {
        int m = 16 * tt + l16;
        f32x4 v = acc[a][tt];
        unsigned int p0 = (unsigned int)f2b(fmaxf(v[0], 0.f)) | ((unsigned int)f2b(fmaxf(v[1], 0.f)) << 16);
        unsigned int p1 = (unsigned int)f2b(fmaxf(v[2], 0.f)) | ((unsigned int)f2b(fmaxf(v[3], 0.f)) << 16);
        int slot = (dg & 16) | ((dg ^ l16) & 15);
        uint2 pp; pp.x = p0; pp.y = p1;
        *(uint2*)(Xb + m * 256 + slot * 8 + qodd) = pp;
      }
    }
    __syncthreads();

    // ---- layer 2: wave w -> edges [16w,16w+16), all 32 classes ----
    f32x4 acc2[2];
    acc2[0] = b2init[0]; acc2[1] = b2init[1];
    const int mrow = 16 * w + l16;
    const unsigned short* yrow = Xb + mrow * 256;
    #pragma unroll
    for (int kk = 0; kk < 8; ++kk) {
      int slot = (4 * kk + q) ^ l16;
      bf16x8 yfrag = *(const bf16x8*)(yrow + slot * 8);
      #pragma unroll
      for (int ct = 0; ct < 2; ++ct) {
        bf16x8 wf = *(const bf16x8*)(W2b + (16 * ct + l16) * H + kk * 32 + q * 8);
        acc2[ct] = __builtin_amdgcn_mfma_f32_16x16x32_bf16(wf, yfrag, acc2[ct], 0, 0, 0);
      }
    }
    int e = t * MT + mrow;
    if (e < E) {
      #pragma unroll
      for (int ct = 0; ct < 2; ++ct)
        *(f32x4*)(out + (size_t)e * CLS + 16 * ct + 4 * q) = acc2[ct];
    }
    buf ^= 1;
  }
}

// ---------------- fallback v1 (ws fits weights only) --------------------------
__global__ __launch_bounds__(256, 2)
void edge_mlp_v1(const float* __restrict__ emb, const void* __restrict__ eidx,
                 const unsigned short* __restrict__ W1b, const unsigned short* __restrict__ W2b,
                 const float* __restrict__ b1, const float* __restrict__ b2,
                 const int* __restrict__ flag64,
                 float* __restrict__ out, int E, int ntiles) {
  __shared__ unsigned short Xsp[MT * LSTR];
  const int tid  = threadIdx.x;
  const int lane = tid & 63;
  const int w    = tid >> 6;
  const int l16  = lane & 15;
  const int q    = lane >> 4;
  const int is64 = *flag64;

  bf16x8 afr[4][8];
  #pragma unroll
  for (int a = 0; a < 4; ++a) {
    const unsigned short* rp = W1b + (64 * w + 16 * a + l16) * K2 + q * 8;
    #pragma unroll
    for (int kk = 0; kk < 8; ++kk) afr[a][kk] = *(const bf16x8*)(rp + kk * 32);
  }
  f32x4 binit[4];
  #pragma unroll
  for (int a = 0; a < 4; ++a) binit[a] = *(const f32x4*)(b1 + 64 * w + 16 * a + 4 * q);
  f32x4 b2init[2];
  #pragma unroll
  for (int ct = 0; ct < 2; ++ct) b2init[ct] = *(const f32x4*)(b2 + 16 * ct + 4 * q);

  for (int t = blockIdx.x; t < ntiles; t += gridDim.x) {
    const int e0 = t * MT;
    #pragma unroll
    for (int c = 0; c < 8; ++c) {
      int chunk = tid + c * 256;
      int m = chunk >> 5, col8 = chunk & 31;
      int e = e0 + m; if (e >= E) e = E - 1;
      int iofs = (col8 < 16) ? e : (E + e);
      long long node = is64 ? ((const long long*)eidx)[iofs] : (long long)(((const int*)eidx)[iofs]);
      const float* gp = emb + (int)node * D + (col8 & 15) * 8;
      f32x4 lo = *(const f32x4*)gp, hi = *(const f32x4*)(gp + 4);
      ushort8 v;
      v[0] = f2b(lo[0]); v[1] = f2b(lo[1]); v[2] = f2b(lo[2]); v[3] = f2b(lo[3]);
      v[4] = f2b(hi[0]); v[5] = f2b(hi[1]); v[6] = f2b(hi[2]); v[7] = f2b(hi[3]);
      *(ushort8*)&Xsp[m * LSTR + col8 * 8] = v;
    }
    __syncthreads();
    f32x4 acc[4][4];
    #pragma unroll
    for (int a = 0; a < 4; ++a)
      #pragma unroll
      for (int tt = 0; tt < 4; ++tt) acc[a][tt] = binit[a];
    #pragma unroll
    for (int tt = 0; tt < 4; ++tt) {
      #pragma unroll
      for (int kk = 0; kk < 8; ++kk) {
        bf16x8 bfrag = *(const bf16x8*)&Xsp[(16 * tt + l16) * LSTR + kk * 32 + q * 8];
        #pragma unroll
        for (int a = 0; a < 4; ++a)
          acc[a][tt] = __builtin_amdgcn_mfma_f32_16x16x32_bf16(afr[a][kk], bfrag, acc[a][tt], 0, 0, 0);
      }
    }
    __syncthreads();
    #pragma unroll
    for (int a = 0; a < 4; ++a) {
      int n0 = 64 * w + 16 * a + 4 * q;
      #pragma unroll
      for (int tt = 0; tt < 4; ++tt) {
        f32x4 v = acc[a][tt];
        unsigned int p0 = (unsigned int)f2b(fmaxf(v[0], 0.f)) | ((unsigned int)f2b(fmaxf(v[1], 0.f)) << 16);
        unsigned int p1 = (unsigned int)f2b(fmaxf(v[2], 0.f)) | ((unsigned int)f2b(fmaxf(v[3], 0.f)) << 16);
        uint2 pp; pp.x = p0; pp.y = p1;
        *(uint2*)&Xsp[(16 * tt + l16) * LSTR + n0] = pp;
      }
    }
    __syncthreads();
    f32x4 acc2[2];
    acc2[0] = b2init[0]; acc2[1] = b2init[1];
    const int mrow = 16 * w + l16;
    #pragma unroll
    for (int kk = 0; kk < 8; ++kk) {
      bf16x8 yfrag = *(const bf16x8*)&Xsp[mrow * LSTR + kk * 32 + q * 8];
      #pragma unroll
      for (int ct = 0; ct < 2; ++ct) {
        bf16x8 wf = *(const bf16x8*)(W2b + (16 * ct + l16) * H + kk * 32 + q * 8);
        acc2[ct] = __builtin_amdgcn_mfma_f32_16x16x32_bf16(wf, yfrag, acc2[ct], 0, 0, 0);
      }
    }
    int e = e0 + mrow;
    if (e < E) {
      #pragma unroll
      for (int ct = 0; ct < 2; ++ct)
        *(f32x4*)(out + (size_t)e * CLS + 16 * ct + 4 * q) = acc2[ct];
    }
    __syncthreads();
  }
}

// ---------------- last-resort naive ------------------------------------------
__global__ void edge_mlp_naive(const float* __restrict__ emb, const void* __restrict__ eidx,
                               const float* __restrict__ W1, const float* __restrict__ b1,
                               const float* __restrict__ W2, const float* __restrict__ b2,
                               float* __restrict__ out, int E) {
  __shared__ float x[K2];
  __shared__ float y[H];
  __shared__ int flag;
  int e = blockIdx.x;
  if (threadIdx.x == 0) {
    const unsigned int* p = (const unsigned int*)eidx;
    int is64 = 1;
    for (int j = 0; j < 16; ++j) if (p[2 * j + 1] != 0u) { is64 = 0; break; }
    flag = is64;
  }
  __syncthreads();
  int tid = threadIdx.x;
  long long s, d;
  if (flag) { s = ((const long long*)eidx)[e]; d = ((const long long*)eidx)[E + e]; }
  else      { s = ((const int*)eidx)[e];       d = ((const int*)eidx)[E + e]; }
  if (tid < D) { x[tid] = emb[(int)s * D + tid]; x[D + tid] = emb[(int)d * D + tid]; }
  __syncthreads();
  float acc = b1[tid];
  const float* wr = W1 + tid * K2;
  for (int k = 0; k < K2; ++k) acc += x[k] * wr[k];
  y[tid] = fmaxf(acc, 0.f);
  __syncthreads();
  if (tid < CLS) {
    float a2 = b2[tid];
    const float* w2 = W2 + tid * H;
    for (int k = 0; k < H; ++k) a2 += y[k] * w2[k];
    out[(size_t)e * CLS + tid] = a2;
  }
}

extern "C" void kernel_launch(void* const* d_in, const int* in_sizes, int n_in,
                              void* d_out, int out_size, void* d_ws, size_t ws_size,
                              hipStream_t stream) {
  const float* emb  = (const float*)d_in[0];
  const void*  eidx = d_in[1];
  const float* W1   = (const float*)d_in[2];
  const float* b1   = (const float*)d_in[3];
  const float* W2   = (const float*)d_in[4];
  const float* b2   = (const float*)d_in[5];
  float* out = (float*)d_out;
  const int nodes_elems = in_sizes[0];   // N_NODES * D
  const int E = in_sizes[1] / 2;
  const int ntiles = (E + MT - 1) / MT;

  // ws layout: [tab (nodes_elems bf16)][W1b][W2b][idx32 (2E)][flag]
  size_t off_tab  = 0;
  size_t off_w1   = (off_tab + (size_t)nodes_elems * 2 + 15) & ~(size_t)15;
  size_t off_w2   = off_w1 + (size_t)H * K2 * 2;
  size_t off_idx  = (off_w2 + (size_t)CLS * H * 2 + 15) & ~(size_t)15;
  size_t off_flag = off_idx + (size_t)2 * E * 4;
  size_t need_full    = off_flag + 16;
  size_t need_weights = (size_t)(H * K2 + CLS * H) * 2 + 64;

  if (ws_size >= need_full) {
    unsigned short* tab   = (unsigned short*)((char*)d_ws + off_tab);
    unsigned short* W1b   = (unsigned short*)((char*)d_ws + off_w1);
    unsigned short* W2b   = (unsigned short*)((char*)d_ws + off_w2);
    int*            idx32 = (int*)((char*)d_ws + off_idx);
    int*            flag  = (int*)((char*)d_ws + off_flag);

    prep_weights<<<(H * K2 + 255) / 256, 256, 0, stream>>>(W1, W2, eidx, W1b, W2b, flag);
    prep_table<<<(nodes_elems / 8 + 255) / 256, 256, 0, stream>>>(emb, tab, nodes_elems / 8);
    prep_idx<<<(2 * E + 255) / 256, 256, 0, stream>>>(eidx, idx32, 2 * E);
    edge_mlp2<<<1024, 256, 0, stream>>>(tab, idx32, W1b, W2b, b1, b2, out, E, ntiles);
  } else if (ws_size >= need_weights) {
    unsigned short* W1b = (unsigned short*)d_ws;
    unsigned short* W2b = W1b + H * K2;
    int* flag = (int*)(W2b + CLS * H);
    prep_weights<<<(H * K2 + 255) / 256, 256, 0, stream>>>(W1, W2, eidx, W1b, W2b, flag);
    edge_mlp_v1<<<1024, 256, 0, stream>>>(emb, eidx, W1b, W2b, b1, b2, flag, out, E, ntiles);
  } else {
    edge_mlp_naive<<<E, H, 0, stream>>>(emb, eidx, W1, b1, W2, b2, out, E);
  }
}